// Round 1
// baseline (75.118 us; speedup 1.0000x reference)
//
#include <hip/hip_runtime.h>
#include <hip/hip_bf16.h>

// MaskDICELoss: B=512 rows, L=65536 cols.
// loss_b = 1 - (2*sum(p*t)+1)/(sum(p+t)+1), p = softmax over valid entries.
// Online-softmax single pass: per row need (max, sum_exp, sum_exp*t, sum_t).
// den_sum = 1 + sum_t exactly enough (softmax sums to 1; threshold is 2e-2).

#define ROWS 512
#define COLS 65536

__device__ __forceinline__ void combine(float& m, float& s, float& se,
                                        float m2, float s2, float se2) {
    float nm = fmaxf(m, m2);
    float r1 = __expf(m - nm);
    float r2 = __expf(m2 - nm);
    s  = s  * r1 + s2  * r2;
    se = se * r1 + se2 * r2;
    m  = nm;
}

__global__ __launch_bounds__(1024)
void row_loss_kernel(const float* __restrict__ logits,
                     const float* __restrict__ tmask,
                     const int*   __restrict__ valid,
                     float* __restrict__ row_loss) {
    const int row = blockIdx.x;
    const size_t base = (size_t)row * COLS;
    const float4* lg = (const float4*)(logits + base);
    const float4* tm = (const float4*)(tmask + base);
    const int4*   vd = (const int4*)(valid + base);
    const int tid = threadIdx.x;
    const int n4 = COLS / 4;  // 16384

    float m = -1e30f, s = 0.f, se = 0.f, st = 0.f;

    for (int j = tid; j < n4; j += 1024) {
        float4 l4 = lg[j];
        float4 t4 = tm[j];
        int4   v4 = vd[j];

        float v0 = v4.x ? 1.f : 0.f, v1 = v4.y ? 1.f : 0.f;
        float v2 = v4.z ? 1.f : 0.f, v3 = v4.w ? 1.f : 0.f;
        // masked logits: invalid -> very negative (exp underflows to 0)
        float a0 = v4.x ? l4.x : -1e30f;
        float a1 = v4.y ? l4.y : -1e30f;
        float a2 = v4.z ? l4.z : -1e30f;
        float a3 = v4.w ? l4.w : -1e30f;
        float t0 = v0 * t4.x, t1 = v1 * t4.y, t2 = v2 * t4.z, t3 = v3 * t4.w;

        float mx = fmaxf(fmaxf(a0, a1), fmaxf(a2, a3));
        float nm = fmaxf(m, mx);
        float r  = __expf(m - nm);   // rescale old state (1.0 when no new max)
        s *= r; se *= r;
        float e0 = v0 * __expf(a0 - nm);
        float e1 = v1 * __expf(a1 - nm);
        float e2 = v2 * __expf(a2 - nm);
        float e3 = v3 * __expf(a3 - nm);
        s  += (e0 + e1) + (e2 + e3);
        se += (e0 * t0 + e1 * t1) + (e2 * t2 + e3 * t3);
        st += (t0 + t1) + (t2 + t3);
        m = nm;
    }

    // wave (64-lane) reduction
    #pragma unroll
    for (int off = 32; off > 0; off >>= 1) {
        float m2  = __shfl_xor(m, off);
        float s2  = __shfl_xor(s, off);
        float se2 = __shfl_xor(se, off);
        float st2 = __shfl_xor(st, off);
        combine(m, s, se, m2, s2, se2);
        st += st2;
    }

    __shared__ float sm[16], ss[16], sse[16], sst[16];
    const int wave = tid >> 6, lane = tid & 63;
    if (lane == 0) { sm[wave] = m; ss[wave] = s; sse[wave] = se; sst[wave] = st; }
    __syncthreads();

    if (tid == 0) {
        float M = sm[0], S = ss[0], SE = sse[0], ST = sst[0];
        #pragma unroll
        for (int w = 1; w < 16; ++w) {
            combine(M, S, SE, sm[w], ss[w], sse[w]);
            ST += sst[w];
        }
        float num = 2.f * SE / S;           // num_sum
        // den_sum = 1 + ST; loss = 1 - (num+1)/(den+1)
        row_loss[row] = 1.f - (num + 1.f) / (ST + 2.f);
    }
}

__global__ __launch_bounds__(512)
void mean_kernel(const float* __restrict__ rl, float* __restrict__ out) {
    const int tid = threadIdx.x;  // 512 threads, one per row
    float x = rl[tid];
    #pragma unroll
    for (int off = 32; off > 0; off >>= 1) x += __shfl_xor(x, off);
    __shared__ float sw[8];
    const int wave = tid >> 6, lane = tid & 63;
    if (lane == 0) sw[wave] = x;
    __syncthreads();
    if (tid == 0) {
        float t = 0.f;
        #pragma unroll
        for (int w = 0; w < 8; ++w) t += sw[w];
        out[0] = t / (float)ROWS;
    }
}

extern "C" void kernel_launch(void* const* d_in, const int* in_sizes, int n_in,
                              void* d_out, int out_size, void* d_ws, size_t ws_size,
                              hipStream_t stream) {
    const float* logits = (const float*)d_in[0];
    const float* tmask  = (const float*)d_in[1];
    const int*   valid  = (const int*)d_in[2];
    float* rl  = (float*)d_ws;          // 512 floats of scratch
    float* out = (float*)d_out;

    row_loss_kernel<<<ROWS, 1024, 0, stream>>>(logits, tmask, valid, rl);
    mean_kernel<<<1, 512, 0, stream>>>(rl, out);
}